// Round 4
// baseline (664.055 us; speedup 1.0000x reference)
//
#include <hip/hip_runtime.h>
#include <stdint.h>

typedef __bf16 bf16x8 __attribute__((ext_vector_type(8)));
typedef float  f32x4  __attribute__((ext_vector_type(4)));

constexpr int NB = 32, TT = 2048, JJ = 512, DD = 256;
constexpr int BM = 128, BN = 128, BK = 64;
constexpr int KSTEPS = DD / BK;   // 4

// LDS (exactly 32 KB -> 5 blocks/CU):
//   sA [0,16384):     bf16[128][64], 128B rows, 16B chunk c stored at slot c^(row&7)
//   sB [16384,32768): same
//   c_s/q_s alias sA[0:1024) after the k-loop (guarded by barrier).

__global__ __launch_bounds__(256, 5)
void sim_kernel(const float* __restrict__ ctx, const float* __restrict__ que,
                const float* __restrict__ wvec, float* __restrict__ out)
{
    __shared__ __align__(1024) unsigned char lds[32768];
    float* c_s = (float*)lds;
    float* q_s = (float*)(lds + 512);

    const int tid = threadIdx.x;
    const int l   = tid & 63;
    const int wid = tid >> 6;

    // XCD-aware swizzle: each XCD gets 256 consecutive work-ids.
    const int pb = blockIdx.x;
    const int id = (pb & 7) * 256 + (pb >> 3);
    const int n0 = (id & 3) * BN;
    const int m0 = ((id >> 2) & 15) * BM;
    const int bI = id >> 6;

    // ---- staging geometry: thread owns rows {wid*8 + (l>>3) + 32i}, k-chunk l&7 (8 f32)
    const int ch = l & 7;
    const int r8 = l >> 3;
    const int rbase = wid * 8 + r8;
    const int slot = ((ch ^ r8) << 4);           // swizzled 16B slot (lane-constant)

    const float* srcA0 = ctx + ((size_t)bI * TT + m0 + rbase) * DD + ch * 8;
    const float* srcB0 = que + ((size_t)bI * JJ + n0 + rbase) * DD + ch * 8;
    const float* wc_p = wvec + ch * 8;
    const float* wq_p = wvec + DD + ch * 8;
    const float* wm_p = wvec + 2 * DD + ch * 8;

    f32x4 a0[4], a1[4], b0[4], b1[4];
    f32x4 wc0, wc1, wq0, wq1, wm0, wm1;

    auto issue = [&](int k) {
        const int k0 = k * BK;
        #pragma unroll
        for (int i = 0; i < 4; ++i) {
            const float* sa = srcA0 + (size_t)i * 32 * DD + k0;
            a0[i] = *(const f32x4*)sa;  a1[i] = *(const f32x4*)(sa + 4);
            const float* sb = srcB0 + (size_t)i * 32 * DD + k0;
            b0[i] = *(const f32x4*)sb;  b1[i] = *(const f32x4*)(sb + 4);
        }
        wm0 = *(const f32x4*)(wm_p + k0);  wm1 = *(const f32x4*)(wm_p + k0 + 4);
        wc0 = *(const f32x4*)(wc_p + k0);  wc1 = *(const f32x4*)(wc_p + k0 + 4);
        wq0 = *(const f32x4*)(wq_p + k0);  wq1 = *(const f32x4*)(wq_p + k0 + 4);
    };

    issue(0);

    f32x4 acc[4][4];
    #pragma unroll
    for (int m = 0; m < 4; ++m)
        #pragma unroll
        for (int n = 0; n < 4; ++n) acc[m][n] = f32x4{0.f, 0.f, 0.f, 0.f};

    const int wm_0 = (wid >> 1) * 64;
    const int wn_0 = (wid & 1) * 64;
    const int lr = l & 15;
    const int hi = l >> 4;
    const int sk = lr & 7;          // frag-read swizzle key

    float cacc[4] = {0.f, 0.f, 0.f, 0.f};
    float qacc[4] = {0.f, 0.f, 0.f, 0.f};

    #pragma unroll
    for (int k = 0; k < KSTEPS; ++k) {
        // phase 1: all waves done reading tile k-1 (lgkm-waited before their MFMAs)
        __builtin_amdgcn_sched_barrier(0);
        __builtin_amdgcn_s_barrier();
        __builtin_amdgcn_sched_barrier(0);

        // cvt once per element + term dots + swizzled ds_write (compiler vmcnt-waits staged regs)
        #pragma unroll
        for (int i = 0; i < 4; ++i) {
            bf16x8 pa, pb2;
            float cp = 0.f, qp = 0.f;
            #pragma unroll
            for (int j = 0; j < 4; ++j) {
                const float xa0 = a0[i][j], xa1 = a1[i][j];
                const float xb0 = b0[i][j], xb1 = b1[i][j];
                pa[j]     = (__bf16)(xa0 * wm0[j]);
                pa[4 + j] = (__bf16)(xa1 * wm1[j]);
                pb2[j]     = (__bf16)xb0;
                pb2[4 + j] = (__bf16)xb1;
                cp += xa0 * wc0[j] + xa1 * wc1[j];
                qp += xb0 * wq0[j] + xb1 * wq1[j];
            }
            cacc[i] += cp;  qacc[i] += qp;
            *(bf16x8*)(lds +         (rbase + i * 32) * 128 + slot) = pa;
            *(bf16x8*)(lds + 16384 + (rbase + i * 32) * 128 + slot) = pb2;
        }
        if (k + 1 < KSTEPS) issue(k + 1);   // flight covered by MFMA phase below

        asm volatile("s_waitcnt lgkmcnt(0)" ::: "memory");   // ds_writes retired
        __builtin_amdgcn_sched_barrier(0);
        __builtin_amdgcn_s_barrier();
        __builtin_amdgcn_sched_barrier(0);

        // fragments + MFMA: 2 k-windows x 16
        #pragma unroll
        for (int kk = 0; kk < 2; ++kk) {
            const int c = kk * 4 + hi;
            bf16x8 af[4], bfr[4];
            #pragma unroll
            for (int m = 0; m < 4; ++m) {
                const int r = wm_0 + m * 16 + lr;
                af[m] = *(const bf16x8*)(lds + r * 128 + ((c ^ sk) << 4));
            }
            #pragma unroll
            for (int n = 0; n < 4; ++n) {
                const int r = wn_0 + n * 16 + lr;
                bfr[n] = *(const bf16x8*)(lds + 16384 + r * 128 + ((c ^ sk) << 4));
            }
            __builtin_amdgcn_s_setprio(1);
            #pragma unroll
            for (int m = 0; m < 4; ++m)
                #pragma unroll
                for (int n = 0; n < 4; ++n)
                    acc[m][n] = __builtin_amdgcn_mfma_f32_16x16x32_bf16(af[m], bfr[n], acc[m][n], 0, 0, 0);
            __builtin_amdgcn_s_setprio(0);
        }
    }

    // ---- terms: reduce across the 8 k-chunk lanes, then park in LDS (aliases sA)
    __builtin_amdgcn_sched_barrier(0);
    __builtin_amdgcn_s_barrier();        // all frag reads done -> sA reusable

    #pragma unroll
    for (int i = 0; i < 4; ++i) {
        float c = cacc[i], q = qacc[i];
        c += __shfl_xor(c, 1); c += __shfl_xor(c, 2); c += __shfl_xor(c, 4);
        q += __shfl_xor(q, 1); q += __shfl_xor(q, 2); q += __shfl_xor(q, 4);
        if (ch == 0) { c_s[rbase + i * 32] = c; q_s[rbase + i * 32] = q; }
    }
    __syncthreads();   // no VMEM outstanding; drains lgkm so c_s/q_s visible

    // ---- epilogue: D lane mapping col=l&15, row=hi*4+q
    const int lq = hi * 4;
    #pragma unroll
    for (int m = 0; m < 4; ++m) {
        const int rowL = wm_0 + m * 16 + lq;
        const f32x4 cv = *(f32x4*)(c_s + rowL);
        #pragma unroll
        for (int n = 0; n < 4; ++n) {
            const int colL = wn_0 + n * 16 + lr;
            const float qv = q_s[colL];
            float* dst = out + ((size_t)bI * TT + m0 + rowL) * JJ + (n0 + colL);
            const f32x4 v = acc[m][n];
            #pragma unroll
            for (int q = 0; q < 4; ++q)
                dst[(size_t)q * JJ] = v[q] + cv[q] + qv;
        }
    }
}

extern "C" void kernel_launch(void* const* d_in, const int* in_sizes, int n_in,
                              void* d_out, int out_size, void* d_ws, size_t ws_size,
                              hipStream_t stream) {
    (void)in_sizes; (void)n_in; (void)d_ws; (void)ws_size; (void)out_size;
    const float* ctx = (const float*)d_in[0];
    const float* que = (const float*)d_in[1];
    const float* wv  = (const float*)d_in[2];
    float* out = (float*)d_out;

    sim_kernel<<<dim3(2048), dim3(256), 0, stream>>>(ctx, que, wv, out);
}

// Round 5
// 56.467 us; speedup vs baseline: 11.7600x; 11.7600x over previous
//
#include <hip/hip_runtime.h>
#include <stdint.h>

typedef __bf16 bf16x8 __attribute__((ext_vector_type(8)));
typedef float  f32x4  __attribute__((ext_vector_type(4)));

typedef __attribute__((address_space(1))) const void g_void;
typedef __attribute__((address_space(3))) void l_void;

constexpr int NB = 32, TT = 2048, JJ = 512, DD = 256;
constexpr int CTX_ROWS = NB * TT;                 // 65536
constexpr int QUE_ROWS = NB * JJ;                 // 16384
constexpr int ALL_ROWS = CTX_ROWS + QUE_ROWS;     // 81920

// d_ws layout (bytes):
//   ctxb  [0,        33554432)   bf16[32][2048][256]
//   queb  [33554432, 41943040)   bf16[32][512][256]
//   cterm [41943040, 42205184)   f32[32][2048]
//   qterm [42205184, 42270720)   f32[32][512]
constexpr size_t WS_QUEB  = 33554432;
constexpr size_t WS_CTERM = 41943040;
constexpr size_t WS_QTERM = 42205184;
constexpr size_t WS_NEED  = 42270720;

// ================= kernel 1: convert + term dots (memory-bound) =============
__global__ __launch_bounds__(256)
void prep_kernel(const float* __restrict__ ctx, const float* __restrict__ que,
                 const float* __restrict__ wvec,
                 __bf16* __restrict__ ctxb, __bf16* __restrict__ queb,
                 float* __restrict__ cterm, float* __restrict__ qterm)
{
    const int tid  = threadIdx.x;
    const int colg = tid & 31;        // 32 col-groups x 8 f32 = 256
    const int rloc = tid >> 5;        // 8 rows per block
    const int k0   = colg * 8;

    const f32x4 wc0 = *(const f32x4*)(wvec + k0);
    const f32x4 wc1 = *(const f32x4*)(wvec + k0 + 4);
    const f32x4 wq0 = *(const f32x4*)(wvec + DD + k0);
    const f32x4 wq1 = *(const f32x4*)(wvec + DD + k0 + 4);
    const f32x4 wm0 = *(const f32x4*)(wvec + 2 * DD + k0);
    const f32x4 wm1 = *(const f32x4*)(wvec + 2 * DD + k0 + 4);

    for (int r = blockIdx.x * 8 + rloc; r < ALL_ROWS; r += gridDim.x * 8) {
        const bool isC = (r < CTX_ROWS);
        const int  rr  = isC ? r : (r - CTX_ROWS);
        const float* src = (isC ? ctx : que) + (size_t)rr * DD + k0;
        const f32x4 x0 = *(const f32x4*)src;
        const f32x4 x1 = *(const f32x4*)(src + 4);

        const f32x4 wd0 = isC ? wc0 : wq0;
        const f32x4 wd1 = isC ? wc1 : wq1;
        float d = x0[0]*wd0[0] + x0[1]*wd0[1] + x0[2]*wd0[2] + x0[3]*wd0[3]
                + x1[0]*wd1[0] + x1[1]*wd1[1] + x1[2]*wd1[2] + x1[3]*wd1[3];
        d += __shfl_xor(d, 1);  d += __shfl_xor(d, 2);  d += __shfl_xor(d, 4);
        d += __shfl_xor(d, 8);  d += __shfl_xor(d, 16);

        bf16x8 pk;
        #pragma unroll
        for (int j = 0; j < 4; ++j) {
            pk[j]     = (__bf16)(isC ? x0[j] * wm0[j] : x0[j]);
            pk[4 + j] = (__bf16)(isC ? x1[j] * wm1[j] : x1[j]);
        }
        *(bf16x8*)((isC ? ctxb : queb) + (size_t)rr * DD + k0) = pk;
        if (colg == 0) (isC ? cterm : qterm)[rr] = d;
    }
}

// ================= kernel 2: bf16 MFMA GEMM + term epilogue ==================
// LDS: sA bf16[128][64] @0 (16KB), sB @16384 (16KB). 16B chunk c of row r at
// slot c^(r&7) (conflict-free ds_read_b128); DMA writes linearly, source
// address carries the inverse permutation (m173 pattern).
__global__ __launch_bounds__(256)
void gemm_kernel(const __bf16* __restrict__ ctxb, const __bf16* __restrict__ queb,
                 const float* __restrict__ cterm, const float* __restrict__ qterm,
                 float* __restrict__ out)
{
    __shared__ __align__(1024) unsigned char lds[32768];

    const int tid = threadIdx.x;
    const int l   = tid & 63;
    const int wid = tid >> 6;

    // XCD-aware swizzle: each XCD gets 256 consecutive work-ids.
    const int pb = blockIdx.x;
    const int id = (pb & 7) * 256 + (pb >> 3);
    const int n0 = (id & 3) * 128;
    const int m0 = ((id >> 2) & 15) * 128;
    const int bI = id >> 6;

    // --- DMA staging: per wave, 4 issues/matrix; issue j covers rows wid*32+j*8..+8
    const int lrow8 = l >> 3;                 // 0..7
    const int lslot = l & 7;
    const int srcsw = (lslot ^ lrow8) << 3;   // swizzled chunk, element offset

    const __bf16* aBase = ctxb + ((size_t)bI * TT + m0 + wid * 32 + lrow8) * DD + srcsw;
    const __bf16* bBase = queb + ((size_t)bI * JJ + n0 + wid * 32 + lrow8) * DD + srcsw;
    unsigned char* ldsA = lds + wid * 4096;
    unsigned char* ldsB = lds + 16384 + wid * 4096;

    auto stage = [&](int k) {
        #pragma unroll
        for (int j = 0; j < 4; ++j) {
            __builtin_amdgcn_global_load_lds((g_void*)(aBase + (size_t)j * 8 * DD + k * 64),
                                             (l_void*)(ldsA + j * 1024), 16, 0, 0);
            __builtin_amdgcn_global_load_lds((g_void*)(bBase + (size_t)j * 8 * DD + k * 64),
                                             (l_void*)(ldsB + j * 1024), 16, 0, 0);
        }
    };

    stage(0);

    f32x4 acc[4][4];
    #pragma unroll
    for (int m = 0; m < 4; ++m)
        #pragma unroll
        for (int n = 0; n < 4; ++n) acc[m][n] = f32x4{0.f, 0.f, 0.f, 0.f};

    const int wm_0 = (wid >> 1) * 64;
    const int wn_0 = (wid & 1) * 64;
    const int lr = l & 15;
    const int hi = l >> 4;

    #pragma unroll
    for (int k = 0; k < 4; ++k) {
        asm volatile("s_waitcnt vmcnt(0)" ::: "memory");   // my 8 DMAs done
        __builtin_amdgcn_s_barrier();                      // everyone's done

        bf16x8 af[2][4], bfr[2][4];
        #pragma unroll
        for (int kk = 0; kk < 2; ++kk) {
            const int c = kk * 4 + hi;
            #pragma unroll
            for (int m = 0; m < 4; ++m) {
                const int r = wm_0 + m * 16 + lr;
                af[kk][m] = *(const bf16x8*)(lds + r * 128 + ((c ^ (r & 7)) << 4));
            }
            #pragma unroll
            for (int n = 0; n < 4; ++n) {
                const int r = wn_0 + n * 16 + lr;
                bfr[kk][n] = *(const bf16x8*)(lds + 16384 + r * 128 + ((c ^ (r & 7)) << 4));
            }
        }
        asm volatile("s_waitcnt lgkmcnt(0)" ::: "memory"); // frag reads retired
        __builtin_amdgcn_sched_barrier(0);
        __builtin_amdgcn_s_barrier();                      // safe to overwrite tile
        if (k < 3) stage(k + 1);                           // DMA flight ∥ MFMA below

        __builtin_amdgcn_s_setprio(1);
        #pragma unroll
        for (int kk = 0; kk < 2; ++kk)
            #pragma unroll
            for (int m = 0; m < 4; ++m)
                #pragma unroll
                for (int n = 0; n < 4; ++n)
                    acc[m][n] = __builtin_amdgcn_mfma_f32_16x16x32_bf16(af[kk][m], bfr[kk][n],
                                                                        acc[m][n], 0, 0, 0);
        __builtin_amdgcn_s_setprio(0);
    }

    // --- epilogue: D mapping col=l&15, row=hi*4+q; terms straight from global (L2-hot)
    const int lq = hi * 4;
    #pragma unroll
    for (int m = 0; m < 4; ++m) {
        const int rowL = wm_0 + m * 16 + lq;
        const f32x4 cv = *(const f32x4*)(cterm + (size_t)bI * TT + m0 + rowL);
        #pragma unroll
        for (int n = 0; n < 4; ++n) {
            const int colL = wn_0 + n * 16 + lr;
            const float qv = qterm[(size_t)bI * JJ + n0 + colL];
            float* dst = out + ((size_t)bI * TT + m0 + rowL) * JJ + (n0 + colL);
            const f32x4 v = acc[m][n];
            #pragma unroll
            for (int q = 0; q < 4; ++q)
                dst[(size_t)q * JJ] = v[q] + cv[q] + qv;
        }
    }
}

// ================= fallback (only if ws too small; correctness-only) ========
__global__ __launch_bounds__(256)
void naive_kernel(const float* __restrict__ ctx, const float* __restrict__ que,
                  const float* __restrict__ wvec, float* __restrict__ out)
{
    const int j = blockIdx.x * 16 + (threadIdx.x & 15);
    const int t = blockIdx.y * 16 + (threadIdx.x >> 4);
    const int b = blockIdx.z;
    const float* cr = ctx + ((size_t)b * TT + t) * DD;
    const float* qr = que + ((size_t)b * JJ + j) * DD;
    float s = 0.f, ct = 0.f, qt = 0.f;
    for (int k = 0; k < DD; ++k) {
        const float cv = cr[k], qv = qr[k];
        s  += cv * wvec[2 * DD + k] * qv;
        ct += cv * wvec[k];
        qt += qv * wvec[DD + k];
    }
    out[((size_t)b * TT + t) * JJ + j] = s + ct + qt;
}

extern "C" void kernel_launch(void* const* d_in, const int* in_sizes, int n_in,
                              void* d_out, int out_size, void* d_ws, size_t ws_size,
                              hipStream_t stream) {
    (void)in_sizes; (void)n_in; (void)out_size;
    const float* ctx = (const float*)d_in[0];
    const float* que = (const float*)d_in[1];
    const float* wv  = (const float*)d_in[2];
    float* out = (float*)d_out;

    if (ws_size < WS_NEED) {
        naive_kernel<<<dim3(JJ / 16, TT / 16, NB), dim3(256), 0, stream>>>(ctx, que, wv, out);
        return;
    }

    __bf16* ctxb = (__bf16*)d_ws;
    __bf16* queb = (__bf16*)((char*)d_ws + WS_QUEB);
    float*  cterm = (float*)((char*)d_ws + WS_CTERM);
    float*  qterm = (float*)((char*)d_ws + WS_QTERM);

    prep_kernel<<<dim3(2048), dim3(256), 0, stream>>>(ctx, que, wv, ctxb, queb, cterm, qterm);
    gemm_kernel<<<dim3(2048), dim3(256), 0, stream>>>(ctxb, queb, cterm, qterm, out);
}